// Round 1
// baseline (1536.879 us; speedup 1.0000x reference)
//
#include <hip/hip_runtime.h>

typedef __attribute__((ext_vector_type(4))) float floatx4;
typedef __attribute__((ext_vector_type(8))) short short8;

// Problem constants: BATCH=256, SEQ=64, HEADS=64, HEAD_DIM=64, EMBED=4096
// P/F region element count: 256*64*64*64 = 16,777,216 rows? No:
//   P: [n][k][h][q] = 256*64*64*64 = 67,108,864 bf16 = 134,217,728 B

__device__ __forceinline__ unsigned short f2bf(float x) {
    union { float f; unsigned u; } v; v.f = x;
    unsigned r = v.u + 0x7FFFu + ((v.u >> 16) & 1u);
    return (unsigned short)(r >> 16);
}
__device__ __forceinline__ float bf2f(unsigned short h) {
    union { unsigned u; float f; } v; v.u = ((unsigned)h) << 16; return v.f;
}
__device__ __forceinline__ unsigned pk2(float a, float b) {
    return (unsigned)f2bf(a) | ((unsigned)f2bf(b) << 16);
}

// ---------------- K1: cast w_out (4096x4096 f32) -> bf16 ----------------
__global__ void cast_w(const float* __restrict__ w, unsigned short* __restrict__ wb) {
    size_t i = ((size_t)blockIdx.x * 256 + threadIdx.x) * 4;
    float4 v = *(const float4*)(w + i);
    ushort4 o;
    o.x = f2bf(v.x); o.y = f2bf(v.y); o.z = f2bf(v.z); o.w = f2bf(v.w);
    *(ushort4*)(wb + i) = o;
}

// ---------------- K2: Vsum[n,h,d] = sum_vh values[n,h,vh*64+d] ----------------
__global__ void vsum_k(const float* __restrict__ values, float* __restrict__ vsum) {
    const int t = threadIdx.x;
    const int d = t & 63;
    const int nh = blockIdx.x * 4 + (t >> 6);   // n*64+h, 0..16383
    const float* base = values + (size_t)nh * 4096 + d;
    float acc = 0.f;
    #pragma unroll
    for (int vh = 0; vh < 64; vh++) acc += base[vh * 64];
    vsum[(size_t)nh * 64 + d] = acc;
}

// ---------------- K3: E = Q.K^T per (n,h); P = exp(E/8) bf16; denom atomics ----
// P layout: [n][k][h][q]  (element = n*262144 + k*4096 + h*64 + q)
// denom layout: [k][h][q] (element = k*4096 + h*64 + q), pre-zeroed
#define QS 68
__global__ __launch_bounds__(256) void energy_k(const float* __restrict__ query,
        const float* __restrict__ keys, const int* __restrict__ mask,
        unsigned short* __restrict__ P, float* __restrict__ denom) {
    __shared__ __align__(16) float QsT[64 * QS];   // [d][q]
    __shared__ __align__(16) float KsT[64 * QS];   // [d][k]
    const int h = blockIdx.y;
    const int nc = blockIdx.x;
    const int t = threadIdx.x;
    const int qg = t >> 4;   // q = qg*4 + a
    const int kg = t & 15;   // k = kg*4 + b
    float dacc[16];
    #pragma unroll
    for (int i = 0; i < 16; i++) dacc[i] = 0.f;
    unsigned* Pu = (unsigned*)P;

    for (int n = nc * 16; n < nc * 16 + 16; n++) {
        if (mask[n * 64 + h] == 0) {
            // masked: entire (n,h) slice of P is zero (uniform branch per block)
            const size_t b32 = (size_t)n * 131072 + (size_t)h * 32;
            #pragma unroll
            for (int i = 0; i < 8; i++) {
                int idx2 = i * 256 + t;                 // 0..2047 (u32 pairs)
                Pu[b32 + (size_t)(idx2 >> 5) * 2048 + (idx2 & 31)] = 0u;
            }
            continue;
        }
        const float* qsrc = query + ((size_t)n * 64 + h) * 4096;
        const float* ksrc = keys + ((size_t)n * 64 + h) * 4096;
        __syncthreads();   // prior iter's LDS reads done before overwrite
        #pragma unroll
        for (int i = 0; i < 4; i++) {
            int v = i * 256 + t;           // float4 id
            int row = v >> 4;              // q or k index
            int d0 = (v & 15) * 4;
            float4 q4 = *(const float4*)(qsrc + (size_t)v * 4);
            float4 k4 = *(const float4*)(ksrc + (size_t)v * 4);
            QsT[(d0 + 0) * QS + row] = q4.x;
            QsT[(d0 + 1) * QS + row] = q4.y;
            QsT[(d0 + 2) * QS + row] = q4.z;
            QsT[(d0 + 3) * QS + row] = q4.w;
            KsT[(d0 + 0) * QS + row] = k4.x;
            KsT[(d0 + 1) * QS + row] = k4.y;
            KsT[(d0 + 2) * QS + row] = k4.z;
            KsT[(d0 + 3) * QS + row] = k4.w;
        }
        __syncthreads();
        float e[16];
        #pragma unroll
        for (int i = 0; i < 16; i++) e[i] = 0.f;
        #pragma unroll 8
        for (int d = 0; d < 64; d++) {
            floatx4 qv = *(const floatx4*)(QsT + d * QS + qg * 4);
            floatx4 kv = *(const floatx4*)(KsT + d * QS + kg * 4);
            e[0]  += qv.x * kv.x; e[1]  += qv.x * kv.y; e[2]  += qv.x * kv.z; e[3]  += qv.x * kv.w;
            e[4]  += qv.y * kv.x; e[5]  += qv.y * kv.y; e[6]  += qv.y * kv.z; e[7]  += qv.y * kv.w;
            e[8]  += qv.z * kv.x; e[9]  += qv.z * kv.y; e[10] += qv.z * kv.z; e[11] += qv.z * kv.w;
            e[12] += qv.w * kv.x; e[13] += qv.w * kv.y; e[14] += qv.w * kv.z; e[15] += qv.w * kv.w;
        }
        const size_t pbase = (size_t)n * 262144 + (size_t)h * 64 + qg * 4;
        #pragma unroll
        for (int b = 0; b < 4; b++) {
            float p0 = __expf(e[0 * 4 + b] * 0.125f);
            float p1 = __expf(e[1 * 4 + b] * 0.125f);
            float p2 = __expf(e[2 * 4 + b] * 0.125f);
            float p3 = __expf(e[3 * 4 + b] * 0.125f);
            dacc[0 * 4 + b] += p0; dacc[1 * 4 + b] += p1;
            dacc[2 * 4 + b] += p2; dacc[3 * 4 + b] += p3;
            ushort4 s;
            s.x = f2bf(p0); s.y = f2bf(p1); s.z = f2bf(p2); s.w = f2bf(p3);
            *(ushort4*)(P + pbase + (size_t)(kg * 4 + b) * 4096) = s;
        }
    }
    #pragma unroll
    for (int a = 0; a < 4; a++)
        #pragma unroll
        for (int b = 0; b < 4; b++)
            atomicAdd(denom + ((size_t)(kg * 4 + b) * 64 + h) * 64 + qg * 4 + a,
                      dacc[a * 4 + b]);
}

// ---------------- K4: normalize + PV; writes F in-place over P slice ----------
// block = (kg4 in 0..15, n in 0..255); slice = P[n][kg4*4 .. +3][*][*] (32 KB)
// F layout: [n][k][q][d]  (element = n*262144 + k*4096 + q*64 + d)
#define VSD 68
__global__ __launch_bounds__(256) void pv_k(const unsigned short* P_in,
        const float* __restrict__ denom, const float* __restrict__ vsum,
        unsigned short* F) {
    __shared__ __align__(16) unsigned short attn[4 * 64 * 64];  // [b][h][q] bf16
    __shared__ __align__(16) float Vs[64 * VSD];                // [h][d]
    const int kg4 = blockIdx.x;
    const int n = blockIdx.y;
    const int t = threadIdx.x;
    // Vsum preload
    #pragma unroll
    for (int i = 0; i < 4; i++) {
        int v = i * 256 + t;
        float4 x = *(const float4*)(vsum + (size_t)n * 4096 + (size_t)v * 4);
        int hh = v >> 4, d0 = (v & 15) * 4;
        *(float4*)(Vs + hh * VSD + d0) = x;
    }
    // attn preload + normalize (reads the ENTIRE block-private P slice here)
    const size_t slice = ((size_t)n * 64 + kg4 * 4) * 4096;
    const uint4* Pv = (const uint4*)(P_in + slice);
    const float* dsl = denom + (size_t)kg4 * 4 * 4096;
    uint4* Av = (uint4*)attn;
    #pragma unroll
    for (int i = 0; i < 8; i++) {
        int j = i * 256 + t;                 // 8 bf16 per j
        uint4 raw = Pv[j];
        floatx4 d0 = *(const floatx4*)(dsl + (size_t)j * 8);
        floatx4 d1 = *(const floatx4*)(dsl + (size_t)j * 8 + 4);
        float v0 = bf2f((unsigned short)(raw.x & 0xffff)) * __builtin_amdgcn_rcpf(d0.x);
        float v1 = bf2f((unsigned short)(raw.x >> 16))    * __builtin_amdgcn_rcpf(d0.y);
        float v2 = bf2f((unsigned short)(raw.y & 0xffff)) * __builtin_amdgcn_rcpf(d0.z);
        float v3 = bf2f((unsigned short)(raw.y >> 16))    * __builtin_amdgcn_rcpf(d0.w);
        float v4 = bf2f((unsigned short)(raw.z & 0xffff)) * __builtin_amdgcn_rcpf(d1.x);
        float v5 = bf2f((unsigned short)(raw.z >> 16))    * __builtin_amdgcn_rcpf(d1.y);
        float v6 = bf2f((unsigned short)(raw.w & 0xffff)) * __builtin_amdgcn_rcpf(d1.z);
        float v7 = bf2f((unsigned short)(raw.w >> 16))    * __builtin_amdgcn_rcpf(d1.w);
        uint4 o;
        o.x = pk2(v0, v1); o.y = pk2(v2, v3); o.z = pk2(v4, v5); o.w = pk2(v6, v7);
        Av[j] = o;
    }
    __syncthreads();   // all global reads of the slice complete past this point
    const int qq = t >> 2, dsub = t & 3;
    floatx4 acc[4][4];
    #pragma unroll
    for (int b = 0; b < 4; b++)
        #pragma unroll
        for (int m = 0; m < 4; m++) acc[b][m] = (floatx4)(0.f);
    #pragma unroll 4
    for (int h = 0; h < 64; h++) {
        float a0 = bf2f(attn[(0 * 64 + h) * 64 + qq]);
        float a1 = bf2f(attn[(1 * 64 + h) * 64 + qq]);
        float a2 = bf2f(attn[(2 * 64 + h) * 64 + qq]);
        float a3 = bf2f(attn[(3 * 64 + h) * 64 + qq]);
        floatx4 w0 = *(const floatx4*)(Vs + h * VSD + dsub * 16);
        floatx4 w1 = *(const floatx4*)(Vs + h * VSD + dsub * 16 + 4);
        floatx4 w2 = *(const floatx4*)(Vs + h * VSD + dsub * 16 + 8);
        floatx4 w3 = *(const floatx4*)(Vs + h * VSD + dsub * 16 + 12);
        acc[0][0] += a0 * w0; acc[0][1] += a0 * w1; acc[0][2] += a0 * w2; acc[0][3] += a0 * w3;
        acc[1][0] += a1 * w0; acc[1][1] += a1 * w1; acc[1][2] += a1 * w2; acc[1][3] += a1 * w3;
        acc[2][0] += a2 * w0; acc[2][1] += a2 * w1; acc[2][2] += a2 * w2; acc[2][3] += a2 * w3;
        acc[3][0] += a3 * w0; acc[3][1] += a3 * w1; acc[3][2] += a3 * w2; acc[3][3] += a3 * w3;
    }
    // overwrite own slice with F[n][k][q][d]
    #pragma unroll
    for (int b = 0; b < 4; b++) {
        size_t base = ((size_t)n * 64 + kg4 * 4 + b) * 4096 + qq * 64 + dsub * 16;
        uint4 o0, o1;
        o0.x = pk2(acc[b][0].x, acc[b][0].y); o0.y = pk2(acc[b][0].z, acc[b][0].w);
        o0.z = pk2(acc[b][1].x, acc[b][1].y); o0.w = pk2(acc[b][1].z, acc[b][1].w);
        o1.x = pk2(acc[b][2].x, acc[b][2].y); o1.y = pk2(acc[b][2].z, acc[b][2].w);
        o1.z = pk2(acc[b][3].x, acc[b][3].y); o1.w = pk2(acc[b][3].z, acc[b][3].w);
        *(uint4*)(F + base) = o0;
        *(uint4*)(F + base + 8) = o1;
    }
}

// ---------------- K5: Y = F @ W^T + b, m97-style bf16 MFMA GEMM ----------------
// A = F (16384 x 4096 bf16, rows r' = n*64+k), B = wb (4096 x 4096 bf16, rows e)
// C row = 256*k + n  (permutation of r')
__device__ __forceinline__ void gload_lds16(const unsigned short* g, unsigned short* lds) {
    __builtin_amdgcn_global_load_lds(
        (const __attribute__((address_space(1))) unsigned int*)g,
        (__attribute__((address_space(3))) unsigned int*)lds, 16, 0, 0);
}

__global__ __launch_bounds__(256) void gemm_bt(const unsigned short* __restrict__ A,
        const unsigned short* __restrict__ B, const float* __restrict__ bias,
        float* __restrict__ C) {
    __shared__ __align__(16) unsigned short As[128 * 32];
    __shared__ __align__(16) unsigned short Bs[128 * 32];
    const int t = threadIdx.x;
    const int w = t >> 6, l = t & 63;
    const int m0 = blockIdx.y * 128;
    const int n0 = blockIdx.x * 128;
    const int c0 = w * 64 + l;
    const int c1 = c0 + 256;
    const int rA0 = c0 >> 2, o0 = (c0 & 3) * 8;
    const int rA1 = c1 >> 2, o1 = (c1 & 3) * 8;
    const unsigned short* gA0 = A + (size_t)(m0 + rA0) * 4096 + o0;
    const unsigned short* gA1 = A + (size_t)(m0 + rA1) * 4096 + o1;
    const unsigned short* gB0 = B + (size_t)(n0 + rA0) * 4096 + o0;
    const unsigned short* gB1 = B + (size_t)(n0 + rA1) * 4096 + o1;
    unsigned short* lA0 = As + w * 512;          // wave-uniform LDS bases
    unsigned short* lA1 = As + 2048 + w * 512;
    unsigned short* lB0 = Bs + w * 512;
    unsigned short* lB1 = Bs + 2048 + w * 512;
    const int wr = w >> 1, wc = w & 1, r16 = l & 15, quad = l >> 4;
    floatx4 acc[4][4];
    #pragma unroll
    for (int mi = 0; mi < 4; mi++)
        #pragma unroll
        for (int ni = 0; ni < 4; ni++) acc[mi][ni] = (floatx4)(0.f);

    for (int kb = 0; kb < 128; kb++) {
        const int k0 = kb * 32;
        gload_lds16(gA0 + k0, lA0);
        gload_lds16(gA1 + k0, lA1);
        gload_lds16(gB0 + k0, lB0);
        gload_lds16(gB1 + k0, lB1);
        __syncthreads();
        short8 af[4], bf[4];
        #pragma unroll
        for (int mi = 0; mi < 4; mi++)
            af[mi] = *(const short8*)(As + (wr * 64 + mi * 16 + r16) * 32 + quad * 8);
        #pragma unroll
        for (int ni = 0; ni < 4; ni++)
            bf[ni] = *(const short8*)(Bs + (wc * 64 + ni * 16 + r16) * 32 + quad * 8);
        #pragma unroll
        for (int mi = 0; mi < 4; mi++)
            #pragma unroll
            for (int ni = 0; ni < 4; ni++)
                acc[mi][ni] = __builtin_amdgcn_mfma_f32_16x16x32_bf16(
                    af[mi], bf[ni], acc[mi][ni], 0, 0, 0);
        __syncthreads();
    }
    #pragma unroll
    for (int mi = 0; mi < 4; mi++) {
        #pragma unroll
        for (int ni = 0; ni < 4; ni++) {
            const int col = n0 + wc * 64 + ni * 16 + r16;
            const float bv = bias[col];
            #pragma unroll
            for (int r = 0; r < 4; r++) {
                const int rp = m0 + wr * 64 + mi * 16 + quad * 4 + r;  // r' = n*64+k
                const int crow = ((rp & 63) << 8) | (rp >> 6);          // 256k + n
                C[(size_t)crow * 4096 + col] = acc[mi][ni][r] + bv;
            }
        }
    }
}

// ---------------- launch ----------------
extern "C" void kernel_launch(void* const* d_in, const int* in_sizes, int n_in,
                              void* d_out, int out_size, void* d_ws, size_t ws_size,
                              hipStream_t stream) {
    const float* values = (const float*)d_in[0];
    const float* keys   = (const float*)d_in[1];
    const float* query  = (const float*)d_in[2];
    const int*   mask   = (const int*)d_in[3];
    const float* w_out  = (const float*)d_in[4];
    const float* b_out  = (const float*)d_in[5];
    float* out = (float*)d_out;

    char* ws = (char*)d_ws;
    unsigned short* P  = (unsigned short*)ws;                    // 134,217,728 B (P then F)
    unsigned short* wb = (unsigned short*)(ws + 134217728);      //  33,554,432 B
    float* vsum        = (float*)(ws + 167772160);               //   4,194,304 B
    float* denom       = (float*)(ws + 171966464);               //   1,048,576 B

    hipMemsetAsync(denom, 0, 262144 * sizeof(float), stream);
    cast_w<<<16384, 256, 0, stream>>>(w_out, wb);
    vsum_k<<<4096, 256, 0, stream>>>(values, vsum);
    energy_k<<<dim3(16, 64), 256, 0, stream>>>(query, keys, mask, P, denom);
    pv_k<<<dim3(16, 256), 256, 0, stream>>>(P, denom, vsum, P);
    gemm_bt<<<dim3(32, 128), 256, 0, stream>>>(P, wb, b_out, out);
}

// Round 2
// 1499.280 us; speedup vs baseline: 1.0251x; 1.0251x over previous
//
#include <hip/hip_runtime.h>

typedef __attribute__((ext_vector_type(4))) float floatx4;
typedef __attribute__((ext_vector_type(8))) short short8;

// BATCH=256, SEQ=64, HEADS=64, HEAD_DIM=64, EMBED=4096
// P layout: [n][k][h][q], 256*64*64*64 bf16 = 134,217,728 B (reused as F by pv_k)

__device__ __forceinline__ unsigned short f2bf(float x) {
    union { float f; unsigned u; } v; v.f = x;
    unsigned r = v.u + 0x7FFFu + ((v.u >> 16) & 1u);
    return (unsigned short)(r >> 16);
}
__device__ __forceinline__ float bf2f(unsigned short h) {
    union { unsigned u; float f; } v; v.u = ((unsigned)h) << 16; return v.f;
}
__device__ __forceinline__ unsigned pk2(float a, float b) {
    return (unsigned)f2bf(a) | ((unsigned)f2bf(b) << 16);
}

// ---------------- K1: cast w_out (4096x4096 f32) -> bf16 ----------------
__global__ void cast_w(const float* __restrict__ w, unsigned short* __restrict__ wb) {
    size_t i = ((size_t)blockIdx.x * 256 + threadIdx.x) * 4;
    float4 v = *(const float4*)(w + i);
    ushort4 o;
    o.x = f2bf(v.x); o.y = f2bf(v.y); o.z = f2bf(v.z); o.w = f2bf(v.w);
    *(ushort4*)(wb + i) = o;
}

// ---------------- K2: Vsum[n,h,d] = sum_vh values[n,h,vh*64+d] ----------------
__global__ void vsum_k(const float* __restrict__ values, float* __restrict__ vsum) {
    const int t = threadIdx.x;
    const int d = t & 63;
    const int nh = blockIdx.x * 4 + (t >> 6);   // n*64+h
    const float* base = values + (size_t)nh * 4096 + d;
    float acc = 0.f;
    #pragma unroll
    for (int vh = 0; vh < 64; vh++) acc += base[vh * 64];
    vsum[(size_t)nh * 64 + d] = acc;
}

// ---------------- K3 v2: MFMA energy. Et[k,q] = K.Q^T per (n,h); P=exp(E/8) ----
// Grid (hquarter=4, n=256). Block: 4 waves, each owns a 32x32 (k,q) quadrant.
// Q/K fragments loaded DIRECTLY from global f32 (row layout [q][d] is already
// fragment-shaped), cast to bf16 in-register. P staged via 32KB LDS tile in
// h-chunks of 4 for coalesced 16B global stores. No atomics (see denom_k).
union U16 { uint4 u; short8 s; };

__global__ __launch_bounds__(256) void energy_k2(const float* __restrict__ query,
        const float* __restrict__ keys, const int* __restrict__ mask,
        unsigned short* __restrict__ P) {
    __shared__ __align__(16) unsigned short T[64 * 256];   // [k][h4*64+q] 32 KB
    const int n = blockIdx.y;
    const int hq = blockIdx.x;
    const int t = threadIdx.x;
    const int w = t >> 6, l = t & 63;
    const int r16 = l & 15, quad = l >> 4;
    const int kw = w >> 1, qw = w & 1;
    unsigned short* Pn = P + (size_t)n * 262144;

    for (int hc = 0; hc < 4; hc++) {
        const int h0 = hq * 16 + hc * 4;
        for (int h4 = 0; h4 < 4; h4++) {
            const int h = h0 + h4;
            if (mask[n * 64 + h] == 0) {
                // masked: p = 0 for the whole (n,h) plane
                #pragma unroll
                for (int mi = 0; mi < 2; mi++)
                    #pragma unroll
                    for (int ni = 0; ni < 2; ni++)
                        #pragma unroll
                        for (int r = 0; r < 4; r++)
                            T[(kw*32 + mi*16 + quad*4 + r) * 256 + h4*64
                              + qw*32 + ni*16 + r16] = 0;
                continue;
            }
            const float* Qr = query + ((size_t)n * 64 + h) * 4096;
            const float* Kr = keys  + ((size_t)n * 64 + h) * 4096;
            short8 af[2][2], bf[2][2];
            #pragma unroll
            for (int mi = 0; mi < 2; mi++)
                #pragma unroll
                for (int ks = 0; ks < 2; ks++) {
                    const float* src = Kr + (kw*32 + mi*16 + r16) * 64 + ks*32 + quad*8;
                    float4 x = *(const float4*)src;
                    float4 y = *(const float4*)(src + 4);
                    U16 u; u.u.x = pk2(x.x, x.y); u.u.y = pk2(x.z, x.w);
                    u.u.z = pk2(y.x, y.y); u.u.w = pk2(y.z, y.w);
                    af[mi][ks] = u.s;
                }
            #pragma unroll
            for (int ni = 0; ni < 2; ni++)
                #pragma unroll
                for (int ks = 0; ks < 2; ks++) {
                    const float* src = Qr + (qw*32 + ni*16 + r16) * 64 + ks*32 + quad*8;
                    float4 x = *(const float4*)src;
                    float4 y = *(const float4*)(src + 4);
                    U16 u; u.u.x = pk2(x.x, x.y); u.u.y = pk2(x.z, x.w);
                    u.u.z = pk2(y.x, y.y); u.u.w = pk2(y.z, y.w);
                    bf[ni][ks] = u.s;
                }
            floatx4 acc[2][2];
            #pragma unroll
            for (int mi = 0; mi < 2; mi++)
                #pragma unroll
                for (int ni = 0; ni < 2; ni++) acc[mi][ni] = (floatx4)(0.f);
            #pragma unroll
            for (int ks = 0; ks < 2; ks++)
                #pragma unroll
                for (int mi = 0; mi < 2; mi++)
                    #pragma unroll
                    for (int ni = 0; ni < 2; ni++)
                        acc[mi][ni] = __builtin_amdgcn_mfma_f32_16x16x32_bf16(
                            af[mi][ks], bf[ni][ks], acc[mi][ni], 0, 0, 0);
            // Et row = k (quad*4+r based), col = q (r16 based)  ->  T[k][h4*64+q]
            #pragma unroll
            for (int mi = 0; mi < 2; mi++)
                #pragma unroll
                for (int ni = 0; ni < 2; ni++)
                    #pragma unroll
                    for (int r = 0; r < 4; r++) {
                        float p = __expf(acc[mi][ni][r] * 0.125f);
                        T[(kw*32 + mi*16 + quad*4 + r) * 256 + h4*64
                          + qw*32 + ni*16 + r16] = f2bf(p);
                    }
        }
        __syncthreads();
        // dump tile: P[n][k][h0..h0+3][q] — 64 segments x 512 B, coalesced
        #pragma unroll
        for (int i = 0; i < 8; i++) {
            int s = i * 256 + t;            // uint4 id, 0..2047
            int k = s >> 5, u = s & 31;
            uint4 v = ((const uint4*)T)[s];
            *(uint4*)(Pn + (size_t)k * 4096 + h0 * 64 + u * 8) = v;
        }
        __syncthreads();
    }
}

// ---------------- K3b: denom[j] = sum_n P[n*262144 + j]  (j over [k][h][q]) ---
__global__ __launch_bounds__(256) void denom_k(const unsigned short* __restrict__ P,
        float* __restrict__ denom) {
    const int j0 = (blockIdx.x * 256 + threadIdx.x) * 4;
    const unsigned short* p = P + j0;
    float s0 = 0.f, s1 = 0.f, s2 = 0.f, s3 = 0.f;
    #pragma unroll 8
    for (int n = 0; n < 256; n++) {
        uint2 v = *(const uint2*)(p + (size_t)n * 262144);
        s0 += bf2f((unsigned short)(v.x & 0xffff));
        s1 += bf2f((unsigned short)(v.x >> 16));
        s2 += bf2f((unsigned short)(v.y & 0xffff));
        s3 += bf2f((unsigned short)(v.y >> 16));
    }
    float4 o; o.x = s0; o.y = s1; o.z = s2; o.w = s3;
    *(float4*)(denom + j0) = o;
}

// ---------------- K4: normalize + PV; writes F in-place over P slice ----------
// block = (kg4 in 0..15, n in 0..255); slice = P[n][kg4*4 .. +3][*][*] (32 KB)
// F layout: [n][k][q][d]  (element = n*262144 + k*4096 + q*64 + d)
#define VSD 68
__global__ __launch_bounds__(256) void pv_k(const unsigned short* P_in,
        const float* __restrict__ denom, const float* __restrict__ vsum,
        unsigned short* F) {
    __shared__ __align__(16) unsigned short attn[4 * 64 * 64];  // [b][h][q] bf16
    __shared__ __align__(16) float Vs[64 * VSD];                // [h][d]
    const int kg4 = blockIdx.x;
    const int n = blockIdx.y;
    const int t = threadIdx.x;
    #pragma unroll
    for (int i = 0; i < 4; i++) {
        int v = i * 256 + t;
        float4 x = *(const float4*)(vsum + (size_t)n * 4096 + (size_t)v * 4);
        int hh = v >> 4, d0 = (v & 15) * 4;
        *(float4*)(Vs + hh * VSD + d0) = x;
    }
    const size_t slice = ((size_t)n * 64 + kg4 * 4) * 4096;
    const uint4* Pv = (const uint4*)(P_in + slice);
    const float* dsl = denom + (size_t)kg4 * 4 * 4096;
    uint4* Av = (uint4*)attn;
    #pragma unroll
    for (int i = 0; i < 8; i++) {
        int j = i * 256 + t;
        uint4 raw = Pv[j];
        floatx4 d0 = *(const floatx4*)(dsl + (size_t)j * 8);
        floatx4 d1 = *(const floatx4*)(dsl + (size_t)j * 8 + 4);
        float v0 = bf2f((unsigned short)(raw.x & 0xffff)) * __builtin_amdgcn_rcpf(d0.x);
        float v1 = bf2f((unsigned short)(raw.x >> 16))    * __builtin_amdgcn_rcpf(d0.y);
        float v2 = bf2f((unsigned short)(raw.y & 0xffff)) * __builtin_amdgcn_rcpf(d0.z);
        float v3 = bf2f((unsigned short)(raw.y >> 16))    * __builtin_amdgcn_rcpf(d0.w);
        float v4 = bf2f((unsigned short)(raw.z & 0xffff)) * __builtin_amdgcn_rcpf(d1.x);
        float v5 = bf2f((unsigned short)(raw.z >> 16))    * __builtin_amdgcn_rcpf(d1.y);
        float v6 = bf2f((unsigned short)(raw.w & 0xffff)) * __builtin_amdgcn_rcpf(d1.z);
        float v7 = bf2f((unsigned short)(raw.w >> 16))    * __builtin_amdgcn_rcpf(d1.w);
        uint4 o;
        o.x = pk2(v0, v1); o.y = pk2(v2, v3); o.z = pk2(v4, v5); o.w = pk2(v6, v7);
        Av[j] = o;
    }
    __syncthreads();
    const int qq = t >> 2, dsub = t & 3;
    floatx4 acc[4][4];
    #pragma unroll
    for (int b = 0; b < 4; b++)
        #pragma unroll
        for (int m = 0; m < 4; m++) acc[b][m] = (floatx4)(0.f);
    #pragma unroll 4
    for (int h = 0; h < 64; h++) {
        float a0 = bf2f(attn[(0 * 64 + h) * 64 + qq]);
        float a1 = bf2f(attn[(1 * 64 + h) * 64 + qq]);
        float a2 = bf2f(attn[(2 * 64 + h) * 64 + qq]);
        float a3 = bf2f(attn[(3 * 64 + h) * 64 + qq]);
        floatx4 w0 = *(const floatx4*)(Vs + h * VSD + dsub * 16);
        floatx4 w1 = *(const floatx4*)(Vs + h * VSD + dsub * 16 + 4);
        floatx4 w2 = *(const floatx4*)(Vs + h * VSD + dsub * 16 + 8);
        floatx4 w3 = *(const floatx4*)(Vs + h * VSD + dsub * 16 + 12);
        acc[0][0] += a0 * w0; acc[0][1] += a0 * w1; acc[0][2] += a0 * w2; acc[0][3] += a0 * w3;
        acc[1][0] += a1 * w0; acc[1][1] += a1 * w1; acc[1][2] += a1 * w2; acc[1][3] += a1 * w3;
        acc[2][0] += a2 * w0; acc[2][1] += a2 * w1; acc[2][2] += a2 * w2; acc[2][3] += a2 * w3;
        acc[3][0] += a3 * w0; acc[3][1] += a3 * w1; acc[3][2] += a3 * w2; acc[3][3] += a3 * w3;
    }
    #pragma unroll
    for (int b = 0; b < 4; b++) {
        size_t base = ((size_t)n * 64 + kg4 * 4 + b) * 4096 + qq * 64 + dsub * 16;
        uint4 o0, o1;
        o0.x = pk2(acc[b][0].x, acc[b][0].y); o0.y = pk2(acc[b][0].z, acc[b][0].w);
        o0.z = pk2(acc[b][1].x, acc[b][1].y); o0.w = pk2(acc[b][1].z, acc[b][1].w);
        o1.x = pk2(acc[b][2].x, acc[b][2].y); o1.y = pk2(acc[b][2].z, acc[b][2].w);
        o1.z = pk2(acc[b][3].x, acc[b][3].y); o1.w = pk2(acc[b][3].z, acc[b][3].w);
        *(uint4*)(F + base) = o0;
        *(uint4*)(F + base + 8) = o1;
    }
}

// ---------------- K5: Y = F @ W^T + b, m97-style bf16 MFMA GEMM ----------------
__device__ __forceinline__ void gload_lds16(const unsigned short* g, unsigned short* lds) {
    __builtin_amdgcn_global_load_lds(
        (const __attribute__((address_space(1))) unsigned int*)g,
        (__attribute__((address_space(3))) unsigned int*)lds, 16, 0, 0);
}

__global__ __launch_bounds__(256) void gemm_bt(const unsigned short* __restrict__ A,
        const unsigned short* __restrict__ B, const float* __restrict__ bias,
        float* __restrict__ C) {
    __shared__ __align__(16) unsigned short As[128 * 32];
    __shared__ __align__(16) unsigned short Bs[128 * 32];
    const int t = threadIdx.x;
    const int w = t >> 6, l = t & 63;
    const int m0 = blockIdx.y * 128;
    const int n0 = blockIdx.x * 128;
    const int c0 = w * 64 + l;
    const int c1 = c0 + 256;
    const int rA0 = c0 >> 2, o0 = (c0 & 3) * 8;
    const int rA1 = c1 >> 2, o1 = (c1 & 3) * 8;
    const unsigned short* gA0 = A + (size_t)(m0 + rA0) * 4096 + o0;
    const unsigned short* gA1 = A + (size_t)(m0 + rA1) * 4096 + o1;
    const unsigned short* gB0 = B + (size_t)(n0 + rA0) * 4096 + o0;
    const unsigned short* gB1 = B + (size_t)(n0 + rA1) * 4096 + o1;
    unsigned short* lA0 = As + w * 512;
    unsigned short* lA1 = As + 2048 + w * 512;
    unsigned short* lB0 = Bs + w * 512;
    unsigned short* lB1 = Bs + 2048 + w * 512;
    const int wr = w >> 1, wc = w & 1, r16 = l & 15, quad = l >> 4;
    floatx4 acc[4][4];
    #pragma unroll
    for (int mi = 0; mi < 4; mi++)
        #pragma unroll
        for (int ni = 0; ni < 4; ni++) acc[mi][ni] = (floatx4)(0.f);

    for (int kb = 0; kb < 128; kb++) {
        const int k0 = kb * 32;
        gload_lds16(gA0 + k0, lA0);
        gload_lds16(gA1 + k0, lA1);
        gload_lds16(gB0 + k0, lB0);
        gload_lds16(gB1 + k0, lB1);
        __syncthreads();
        short8 af[4], bf[4];
        #pragma unroll
        for (int mi = 0; mi < 4; mi++)
            af[mi] = *(const short8*)(As + (wr * 64 + mi * 16 + r16) * 32 + quad * 8);
        #pragma unroll
        for (int ni = 0; ni < 4; ni++)
            bf[ni] = *(const short8*)(Bs + (wc * 64 + ni * 16 + r16) * 32 + quad * 8);
        #pragma unroll
        for (int mi = 0; mi < 4; mi++)
            #pragma unroll
            for (int ni = 0; ni < 4; ni++)
                acc[mi][ni] = __builtin_amdgcn_mfma_f32_16x16x32_bf16(
                    af[mi], bf[ni], acc[mi][ni], 0, 0, 0);
        __syncthreads();
    }
    #pragma unroll
    for (int mi = 0; mi < 4; mi++) {
        #pragma unroll
        for (int ni = 0; ni < 4; ni++) {
            const int col = n0 + wc * 64 + ni * 16 + r16;
            const float bv = bias[col];
            #pragma unroll
            for (int r = 0; r < 4; r++) {
                const int rp = m0 + wr * 64 + mi * 16 + quad * 4 + r;  // r' = n*64+k
                const int crow = ((rp & 63) << 8) | (rp >> 6);          // 256k + n
                C[(size_t)crow * 4096 + col] = acc[mi][ni][r] + bv;
            }
        }
    }
}

// ---------------- launch ----------------
extern "C" void kernel_launch(void* const* d_in, const int* in_sizes, int n_in,
                              void* d_out, int out_size, void* d_ws, size_t ws_size,
                              hipStream_t stream) {
    const float* values = (const float*)d_in[0];
    const float* keys   = (const float*)d_in[1];
    const float* query  = (const float*)d_in[2];
    const int*   mask   = (const int*)d_in[3];
    const float* w_out  = (const float*)d_in[4];
    const float* b_out  = (const float*)d_in[5];
    float* out = (float*)d_out;

    char* ws = (char*)d_ws;
    unsigned short* P  = (unsigned short*)ws;                    // 134,217,728 B (P then F)
    unsigned short* wb = (unsigned short*)(ws + 134217728);      //  33,554,432 B
    float* vsum        = (float*)(ws + 167772160);               //   4,194,304 B
    float* denom       = (float*)(ws + 171966464);               //   1,048,576 B

    cast_w<<<16384, 256, 0, stream>>>(w_out, wb);
    vsum_k<<<4096, 256, 0, stream>>>(values, vsum);
    energy_k2<<<dim3(4, 256), 256, 0, stream>>>(query, keys, mask, P);
    denom_k<<<256, 256, 0, stream>>>(P, denom);
    pv_k<<<dim3(16, 256), 256, 0, stream>>>(P, denom, vsum, P);
    gemm_bt<<<dim3(32, 128), 256, 0, stream>>>(P, wb, b_out, out);
}